// Round 1
// baseline (835.381 us; speedup 1.0000x reference)
//
#include <hip/hip_runtime.h>
#include <climits>

// CenterDependentPool2D: out[b,c,oy,ox] = max over k x k window (stride 2,
// reflect pad, pad_lo=(k-1)/2) where k by d2 = (oy-112)^2+(ox-112)^2:
//   d2<3600 -> 2 | <5625 -> 8 | <8100 -> 14 | <11025 -> 20 | else 26
// All k even.  Fixed staging frame: T row r / col t <-> input (2*oy0-12+r,
// 2*ox0-12+t).  Ring-K window start in frame = 2*l + O, O = (26-K)/2
// (both axes; 12 - O = (K-2)/2 = pad_lo for even K).
// Pipeline per ring (pairs-first; max is associative so this commutes with
// the old windows-first order but halves the heavy stage's row count):
//   VPT[v] = max(T[tbase+2v], T[tbase+2v+1])          (nv = rows-1+K/2 rows)
//   HW[v]  = horizontal K-window of VPT[v]            (nv rows)
//   out[lr]= max_{j<K/2} HW[lr+j]  + per-pixel ring mask

#define IN_SZ 448
#define OUT_SZ 224
#define CENTER 112
#define TILE_X 32
#define TILE_Y 14          // 224 = 14*16, and 112 = 14*8 -> no center straddle
#define TSTR 92            // multiple of 4 -> f4-aligned T rows; 92%32=28
#define VSTR 92
#define HSTR 32
#define NTHREADS 256

#define T_ROWS 52          // 2*(TILE_Y-1) + 26
#define V_ROWS 26          // (TILE_Y-1) + 13
#define GPRC 22            // f4 groups per staged row (88 floats)

__device__ __forceinline__ int reflect448(int g) {
    g = (g < 0) ? -g : g;
    g = (g >= IN_SZ) ? (2 * IN_SZ - 2 - g) : g;
    return g;
}

__device__ __forceinline__ int ring_k(int d2) {
    if (d2 < 3600)  return 2;
    if (d2 < 5625)  return 8;
    if (d2 < 8100)  return 14;
    if (d2 < 11025) return 20;
    return 26;
}

__device__ __forceinline__ int isqrt_floor(int v) {   // exact, v in [0, ~1e6]
    int s = (int)sqrtf((float)v);
    if (s > 0 && s * s > v) --s;
    if ((s + 1) * (s + 1) <= v) ++s;
    return s;
}

__device__ __forceinline__ float4 max4(float4 a, float4 b) {
    return make_float4(fmaxf(a.x, b.x), fmaxf(a.y, b.y),
                       fmaxf(a.z, b.z), fmaxf(a.w, b.w));
}

template <int K>
__device__ __forceinline__ void ring_pass(
    const float* __restrict__ T, float* __restrict__ VPT,
    float* __restrict__ HW, float* __restrict__ op,
    int tid, int lyA, int lyB, int ox0, int oy0)
{
    constexpr int O  = (26 - K) / 2;   // frame offset of window start
    constexpr int KH = K / 2;          // pairs per window
    constexpr int S  = O & 3;          // sub-f4 shift of window base
    constexpr int NF = S + K + 6;      // floats needed per 4-output task
    constexpr int R  = (NF + 3) >> 2;  // f4 reads per HW task
    constexpr int B0 = (O - S) >> 2;   // f4 offset of aligned base
    constexpr int CGN = (GPRC - B0 < 14 + R) ? (GPRC - B0) : (14 + R);

    const int rows  = lyB - lyA + 1;
    const int nv    = rows - 1 + KH;       // pair rows needed
    const int tbase = 2 * lyA + O;         // T row of pair row 0

    // ---- stage 1: vertical pairs of T (each T element read once) ----
    for (int t = tid; t < nv * CGN; t += NTHREADS) {
        const int v = t / CGN, c = B0 + (t - v * CGN);   // CGN constexpr
        const float* r0 = &T[(tbase + 2 * v) * TSTR + 4 * c];
        const float4 a = *(const float4*)r0;
        const float4 b = *(const float4*)(r0 + TSTR);
        *(float4*)&VPT[v * VSTR + 4 * c] = max4(a, b);
    }
    __syncthreads();

    // ---- stage 2: horizontal K-window on each pair row ----
    for (int t = tid; t < nv * 8; t += NTHREADS) {
        const int v = t >> 3, g = t & 7;
        const float4* vrow = (const float4*)&VPT[v * VSTR];
        float f[4 * R];
#pragma unroll
        for (int q = 0; q < R; ++q)
            *(float4*)&f[4 * q] = vrow[2 * g + B0 + q];
        float p[KH + 3];                      // horizontal pair pre-reduce
#pragma unroll
        for (int j = 0; j < KH + 3; ++j)
            p[j] = fmaxf(f[S + 2 * j], f[S + 2 * j + 1]);
        float4 W;
        if constexpr (KH == 1) {
            W = make_float4(p[0], p[1], p[2], p[3]);
        } else {                              // KH in {4,7,10,13}
            float core = p[3];
#pragma unroll
            for (int j = 4; j < KH; ++j) core = fmaxf(core, p[j]);
            W.x = fmaxf(fmaxf(p[0], p[1]), fmaxf(p[2], core));
            W.y = fmaxf(fmaxf(p[1], p[2]), fmaxf(core, p[KH]));
            W.z = fmaxf(fmaxf(p[2], core), fmaxf(p[KH], p[KH + 1]));
            W.w = fmaxf(fmaxf(core, p[KH]), fmaxf(p[KH + 1], p[KH + 2]));
        }
        *(float4*)&HW[v * HSTR + 4 * g] = W;  // dense, conflict-free
    }
    __syncthreads();

    // ---- stage 3: vertical KH-window over HW + per-pixel masked store ----
    for (int t = tid; t < rows * 8; t += NTHREADS) {
        const int lr = t >> 3, g = t & 7;
        float4 m = *(const float4*)&HW[lr * HSTR + 4 * g];
#pragma unroll
        for (int j = 1; j < KH; ++j)
            m = max4(m, *(const float4*)&HW[(lr + j) * HSTR + 4 * g]);
        const int oy  = oy0 + lyA + lr;
        const int dy2 = (oy - CENTER) * (oy - CENTER);
        const int oxb = ox0 + 4 * g;
        float* orow = op + (size_t)oy * OUT_SZ + oxb;
        const float mv[4] = {m.x, m.y, m.z, m.w};
#pragma unroll
        for (int e = 0; e < 4; ++e) {
            const int dx = oxb + e - CENTER;
            if (ring_k(dy2 + dx * dx) == K) orow[e] = mv[e];
        }
    }
    // no trailing sync: next ring's stage 1 writes VPT (not HW); its post-
    // stage-1 barrier orders this stage-3's HW reads before HW is rewritten.
}

__global__ __launch_bounds__(NTHREADS, 5)
void CenterDependentPool2D_kernel(const float* __restrict__ x,
                                  float* __restrict__ out)
{
    __shared__ float T[T_ROWS * TSTR];     // 19,136 B
    __shared__ float VPT[V_ROWS * VSTR];   //  9,568 B
    __shared__ float HW[V_ROWS * HSTR];    //  3,328 B  -> 32,032 B (5 blk/CU)

    const int tid = threadIdx.x;
    const int ox0 = blockIdx.x * TILE_X;
    const int oy0 = blockIdx.y * TILE_Y;
    const int plane = blockIdx.z;

    const float* __restrict__ in = x + (size_t)plane * IN_SZ * IN_SZ;
    float* __restrict__ op = out + (size_t)plane * OUT_SZ * OUT_SZ;

    // dx^2 range over this tile's columns
    const int a = ox0 - CENTER, b = ox0 + TILE_X - 1 - CENTER;
    int xmn2, xmx2;
    if (a > 0)      { xmn2 = a * a; xmx2 = b * b; }
    else if (b < 0) { xmn2 = b * b; xmx2 = a * a; }
    else            { xmn2 = 0; const int m = (-a > b) ? -a : b; xmx2 = m * m; }

    const int R2a[5] = {0, 3600, 5625, 8100, 11025};
    const int R2b[5] = {3600, 5625, 8100, 11025, INT_MAX};

    // per-ring output-row intervals [lyA, lyB] (conservative-safe; the
    // per-pixel ring_k mask in stage 3 guarantees exact coverage)
    int lyA[5], lyB[5];
    const int d0 = oy0 - CENTER;       // oy0 = 14*j; tiles never straddle 112
#pragma unroll
    for (int i = 0; i < 5; ++i) {
        int A = 1, B = 0;
        int shi;
        bool nonempty;
        if (i == 4) { shi = 1000; nonempty = true; }
        else {
            const int hi2 = R2b[i] - 1 - xmn2;
            nonempty = (hi2 >= 0);
            shi = nonempty ? isqrt_floor(hi2) : 0;
        }
        if (nonempty) {
            const int lo2 = R2a[i] - xmx2;
            const int slo = (lo2 <= 0) ? 0 : isqrt_floor(lo2 - 1) + 1;
            if (d0 >= 0) { A = slo - d0; B = shi - d0; }
            else         { const int dp = -d0; A = dp - shi; B = dp - slo; }
            A = A < 0 ? 0 : A;
            B = B > TILE_Y - 1 ? TILE_Y - 1 : B;
        }
        lyA[i] = A; lyB[i] = B;
    }

    // ---- staging: fixed 26-frame, 52 x 88 floats, per-task guarded f4 ----
    // x_org = 2*ox0 - 12 is always 0 mod 4 -> vector loads for every
    // in-bounds float4, including border-tile interiors.
    const int x_org = 2 * ox0 - 12;
    const int y_org = 2 * oy0 - 12;
    for (int t = tid; t < T_ROWS * GPRC; t += NTHREADS) {
        const int r = t / GPRC, c4 = (t - r * GPRC) * 4;   // GPRC constexpr
        const int gy = y_org + r, gx = x_org + c4;
        float4 v;
        if ((unsigned)gy < IN_SZ && (unsigned)gx <= IN_SZ - 4) {
            v = *(const float4*)(in + (size_t)gy * IN_SZ + gx);
        } else {
            const float* rowp = in + (size_t)reflect448(gy) * IN_SZ;
            v.x = rowp[reflect448(gx + 0)];
            v.y = rowp[reflect448(gx + 1)];
            v.z = rowp[reflect448(gx + 2)];
            v.w = rowp[reflect448(gx + 3)];
        }
        *(float4*)&T[r * TSTR + c4] = v;
    }
    __syncthreads();

    if (lyA[0] <= lyB[0]) ring_pass<2 >(T, VPT, HW, op, tid, lyA[0], lyB[0], ox0, oy0);
    if (lyA[1] <= lyB[1]) ring_pass<8 >(T, VPT, HW, op, tid, lyA[1], lyB[1], ox0, oy0);
    if (lyA[2] <= lyB[2]) ring_pass<14>(T, VPT, HW, op, tid, lyA[2], lyB[2], ox0, oy0);
    if (lyA[3] <= lyB[3]) ring_pass<20>(T, VPT, HW, op, tid, lyA[3], lyB[3], ox0, oy0);
    if (lyA[4] <= lyB[4]) ring_pass<26>(T, VPT, HW, op, tid, lyA[4], lyB[4], ox0, oy0);
}

extern "C" void kernel_launch(void* const* d_in, const int* in_sizes, int n_in,
                              void* d_out, int out_size, void* d_ws, size_t ws_size,
                              hipStream_t stream) {
    const float* x = (const float*)d_in[0];
    float* out = (float*)d_out;
    dim3 grid(OUT_SZ / TILE_X, OUT_SZ / TILE_Y, 8 * 64);   // (7, 16, 512)
    dim3 block(NTHREADS, 1, 1);
    hipLaunchKernelGGL(CenterDependentPool2D_kernel, grid, block, 0, stream, x, out);
}

// Round 2
// 811.096 us; speedup vs baseline: 1.0299x; 1.0299x over previous
//
#include <hip/hip_runtime.h>
#include <climits>

// CenterDependentPool2D: out[b,c,oy,ox] = max over k x k window (stride 2,
// reflect pad, pad_lo=(k-1)/2) where k by d2 = (oy-112)^2+(ox-112)^2:
//   d2<3600 -> 2 | <5625 -> 8 | <8100 -> 14 | <11025 -> 20 | else 26
// All k even.  Variable staging frame sized by the tile's kmax, base aligned
// DOWN to a float4 boundary: x_al = 2*ox0 - PLT - D with D = (-PLT) mod 4,
// so every tile stages with vector loads.  T col t <-> input x_al + t,
// T row r <-> input 2*oy0 - PLT + r.  Ring-K horizontal window start in the
// frame = 2*lx + OX, OX = (KMAX-K)/2 + D; vertical = 2*ly + OY,
// OY = (KMAX-K)/2.
// Pipeline per ring (pairs-first; max is associative so pairing rows before
// the horizontal window halves the heavy windowing stage's row count):
//   VPT[v] = max(T[tbase+2v], T[tbase+2v+1])          (nv = rows-1+K/2 rows)
//   HW[v]  = horizontal K-window of VPT[v]            (nv rows)
//   out[lr]= max_{j<K/2} HW[lr+j]  + per-pixel ring mask

#define IN_SZ 448
#define OUT_SZ 224
#define CENTER 112
#define TILE_X 32
#define TILE_Y 14          // 224 = 14*16, and 112 = 14*8 -> no center straddle
#define TSTR 92            // mult of 4; f4-granule stride 23 (odd) for banks
#define VSTR 92
#define HSTR 32
#define NTHREADS 256

#define T_ROWS 52          // 2*(TILE_Y-1) + 26 (max frame)
#define V_ROWS 26          // (TILE_Y-1) + 13

__device__ __forceinline__ int reflect448(int g) {
    g = (g < 0) ? -g : g;
    g = (g >= IN_SZ) ? (2 * IN_SZ - 2 - g) : g;
    return g;
}

__device__ __forceinline__ int ring_k(int d2) {
    if (d2 < 3600)  return 2;
    if (d2 < 5625)  return 8;
    if (d2 < 8100)  return 14;
    if (d2 < 11025) return 20;
    return 26;
}

__device__ __forceinline__ int isqrt_floor(int v) {   // exact, v in [0, ~1e6]
    int s = (int)sqrtf((float)v);
    if (s > 0 && s * s > v) --s;
    if ((s + 1) * (s + 1) <= v) ++s;
    return s;
}

__device__ __forceinline__ float4 max4(float4 a, float4 b) {
    return make_float4(fmaxf(a.x, b.x), fmaxf(a.y, b.y),
                       fmaxf(a.z, b.z), fmaxf(a.w, b.w));
}

template <int K, int KMAX>
__device__ __forceinline__ void ring_pass(
    const float* __restrict__ T, float* __restrict__ VPT,
    float* __restrict__ HW, float* __restrict__ op,
    int tid, int lyA, int lyB, int ox0, int oy0)
{
    constexpr int PLT = KMAX / 2 - 1;      // pad_lo of kmax
    constexpr int D   = (4 - (PLT & 3)) & 3;
    constexpr int OX  = (KMAX - K) / 2 + D; // horiz window offset in frame
    constexpr int OY  = (KMAX - K) / 2;     // vert  window offset in frame
    constexpr int KH  = K / 2;             // pairs per window
    constexpr int S   = OX & 3;            // sub-f4 shift of window base
    constexpr int R   = (S + K + 6 + 3) >> 2;  // f4 reads per HW task
    constexpr int B0  = (OX - S) >> 2;     // f4 offset of aligned base
    constexpr int CGN = 14 + R;            // f4 cols to pair (B0..B0+CGN-1)

    const int rows  = lyB - lyA + 1;
    const int nv    = rows - 1 + KH;       // pair rows needed
    const int tbase = 2 * lyA + OY;        // T row of pair row 0

    // ---- stage 1: vertical pairs of T (each T element read once) ----
    for (int t = tid; t < nv * CGN; t += NTHREADS) {
        const int v = t / CGN, c = B0 + (t - v * CGN);   // CGN constexpr
        const float* r0 = &T[(tbase + 2 * v) * TSTR + 4 * c];
        const float4 a = *(const float4*)r0;
        const float4 b = *(const float4*)(r0 + TSTR);
        *(float4*)&VPT[v * VSTR + 4 * c] = max4(a, b);
    }
    __syncthreads();

    // ---- stage 2: horizontal K-window on each pair row ----
    for (int t = tid; t < nv * 8; t += NTHREADS) {
        const int v = t >> 3, g = t & 7;
        const float4* vrow = (const float4*)&VPT[v * VSTR];
        float f[4 * R];
#pragma unroll
        for (int q = 0; q < R; ++q)
            *(float4*)&f[4 * q] = vrow[2 * g + B0 + q];
        float p[KH + 3];                      // horizontal pair pre-reduce
#pragma unroll
        for (int j = 0; j < KH + 3; ++j)
            p[j] = fmaxf(f[S + 2 * j], f[S + 2 * j + 1]);
        float4 W;
        if constexpr (KH == 1) {
            W = make_float4(p[0], p[1], p[2], p[3]);
        } else {                              // KH in {4,7,10,13}
            float core = p[3];
#pragma unroll
            for (int j = 4; j < KH; ++j) core = fmaxf(core, p[j]);
            W.x = fmaxf(fmaxf(p[0], p[1]), fmaxf(p[2], core));
            W.y = fmaxf(fmaxf(p[1], p[2]), fmaxf(core, p[KH]));
            W.z = fmaxf(fmaxf(p[2], core), fmaxf(p[KH], p[KH + 1]));
            W.w = fmaxf(fmaxf(core, p[KH]), fmaxf(p[KH + 1], p[KH + 2]));
        }
        *(float4*)&HW[v * HSTR + 4 * g] = W;  // dense, conflict-free
    }
    __syncthreads();

    // ---- stage 3: vertical KH-window over HW + per-pixel masked store ----
    for (int t = tid; t < rows * 8; t += NTHREADS) {
        const int lr = t >> 3, g = t & 7;
        float4 m = *(const float4*)&HW[lr * HSTR + 4 * g];
#pragma unroll
        for (int j = 1; j < KH; ++j)
            m = max4(m, *(const float4*)&HW[(lr + j) * HSTR + 4 * g]);
        const int oy  = oy0 + lyA + lr;
        const int dy2 = (oy - CENTER) * (oy - CENTER);
        const int oxb = ox0 + 4 * g;
        float* orow = op + (size_t)oy * OUT_SZ + oxb;
        const float mv[4] = {m.x, m.y, m.z, m.w};
#pragma unroll
        for (int e = 0; e < 4; ++e) {
            const int dx = oxb + e - CENTER;
            if (ring_k(dy2 + dx * dx) == K) orow[e] = mv[e];
        }
    }
    // no trailing sync: next ring's stage 1 writes VPT (not HW); its post-
    // stage-1 barrier orders this stage-3's HW reads before HW is rewritten.
}

template <int KMAX>
__device__ __forceinline__ void stage_and_run(
    float* __restrict__ T, float* __restrict__ VPT, float* __restrict__ HW,
    const float* __restrict__ in, float* __restrict__ op,
    int tid, const int* lyA, const int* lyB, int ox0, int oy0)
{
    constexpr int PLT = KMAX / 2 - 1;
    constexpr int D   = (4 - (PLT & 3)) & 3;     // PLT+D multiple of 4
    constexpr int SPX = 2 * (TILE_X - 1) + KMAX + D;
    constexpr int GPR = (SPX + 3) >> 2;          // f4 groups per staged row
    constexpr int SPY = 2 * (TILE_Y - 1) + KMAX; // staged rows

    // x_al = 2*ox0 - PLT - D is 0 mod 4 (2*ox0 is a multiple of 64)
    const int x_al  = 2 * ox0 - PLT - D;
    const int y_org = 2 * oy0 - PLT;

    for (int t = tid; t < SPY * GPR; t += NTHREADS) {
        const int r = t / GPR, c4 = (t - r * GPR) * 4;   // GPR constexpr
        const int gy = y_org + r, gx = x_al + c4;
        float4 v;
        if ((unsigned)gy < IN_SZ && (unsigned)gx <= IN_SZ - 4) {
            v = *(const float4*)(in + (size_t)gy * IN_SZ + gx);
        } else {
            const float* rowp = in + (size_t)reflect448(gy) * IN_SZ;
            v.x = rowp[reflect448(gx + 0)];
            v.y = rowp[reflect448(gx + 1)];
            v.z = rowp[reflect448(gx + 2)];
            v.w = rowp[reflect448(gx + 3)];
        }
        *(float4*)&T[r * TSTR + c4] = v;
    }
    __syncthreads();

    if (lyA[0] <= lyB[0])
        ring_pass<2, KMAX>(T, VPT, HW, op, tid, lyA[0], lyB[0], ox0, oy0);
    if constexpr (KMAX >= 8)
        if (lyA[1] <= lyB[1])
            ring_pass<8, KMAX>(T, VPT, HW, op, tid, lyA[1], lyB[1], ox0, oy0);
    if constexpr (KMAX >= 14)
        if (lyA[2] <= lyB[2])
            ring_pass<14, KMAX>(T, VPT, HW, op, tid, lyA[2], lyB[2], ox0, oy0);
    if constexpr (KMAX >= 20)
        if (lyA[3] <= lyB[3])
            ring_pass<20, KMAX>(T, VPT, HW, op, tid, lyA[3], lyB[3], ox0, oy0);
    if constexpr (KMAX >= 26)
        if (lyA[4] <= lyB[4])
            ring_pass<26, KMAX>(T, VPT, HW, op, tid, lyA[4], lyB[4], ox0, oy0);
}

__global__ __launch_bounds__(NTHREADS, 5)
void CenterDependentPool2D_kernel(const float* __restrict__ x,
                                  float* __restrict__ out)
{
    __shared__ float T[T_ROWS * TSTR];     // 19,136 B
    __shared__ float VPT[V_ROWS * VSTR];   //  9,568 B
    __shared__ float HW[V_ROWS * HSTR];    //  3,328 B  -> 32,032 B (5 blk/CU)

    const int tid = threadIdx.x;
    const int ox0 = blockIdx.x * TILE_X;
    const int oy0 = blockIdx.y * TILE_Y;
    const int plane = blockIdx.z;

    const float* __restrict__ in = x + (size_t)plane * IN_SZ * IN_SZ;
    float* __restrict__ op = out + (size_t)plane * OUT_SZ * OUT_SZ;

    // dx^2 range over this tile's columns
    const int a = ox0 - CENTER, b = ox0 + TILE_X - 1 - CENTER;
    int xmn2, xmx2;
    if (a > 0)      { xmn2 = a * a; xmx2 = b * b; }
    else if (b < 0) { xmn2 = b * b; xmx2 = a * a; }
    else            { xmn2 = 0; const int m = (-a > b) ? -a : b; xmx2 = m * m; }

    const int R2a[5] = {0, 3600, 5625, 8100, 11025};
    const int R2b[5] = {3600, 5625, 8100, 11025, INT_MAX};
    const int KS[5]  = {2, 8, 14, 20, 26};

    // per-ring output-row intervals [lyA, lyB] (conservative-safe; the
    // per-pixel ring_k mask in stage 3 guarantees exact coverage)
    int lyA[5], lyB[5];
    int kmax = 2;
    const int d0 = oy0 - CENTER;       // oy0 = 14*j; tiles never straddle 112
#pragma unroll
    for (int i = 0; i < 5; ++i) {
        int A = 1, B = 0;
        int shi;
        bool nonempty;
        if (i == 4) { shi = 1000; nonempty = true; }
        else {
            const int hi2 = R2b[i] - 1 - xmn2;
            nonempty = (hi2 >= 0);
            shi = nonempty ? isqrt_floor(hi2) : 0;
        }
        if (nonempty) {
            const int lo2 = R2a[i] - xmx2;
            const int slo = (lo2 <= 0) ? 0 : isqrt_floor(lo2 - 1) + 1;
            if (d0 >= 0) { A = slo - d0; B = shi - d0; }
            else         { const int dp = -d0; A = dp - shi; B = dp - slo; }
            A = A < 0 ? 0 : A;
            B = B > TILE_Y - 1 ? TILE_Y - 1 : B;
        }
        lyA[i] = A; lyB[i] = B;
        if (A <= B) kmax = KS[i];
    }

    switch (kmax) {
        case 2:  stage_and_run<2 >(T, VPT, HW, in, op, tid, lyA, lyB, ox0, oy0); break;
        case 8:  stage_and_run<8 >(T, VPT, HW, in, op, tid, lyA, lyB, ox0, oy0); break;
        case 14: stage_and_run<14>(T, VPT, HW, in, op, tid, lyA, lyB, ox0, oy0); break;
        case 20: stage_and_run<20>(T, VPT, HW, in, op, tid, lyA, lyB, ox0, oy0); break;
        default: stage_and_run<26>(T, VPT, HW, in, op, tid, lyA, lyB, ox0, oy0); break;
    }
}

extern "C" void kernel_launch(void* const* d_in, const int* in_sizes, int n_in,
                              void* d_out, int out_size, void* d_ws, size_t ws_size,
                              hipStream_t stream) {
    const float* x = (const float*)d_in[0];
    float* out = (float*)d_out;
    dim3 grid(OUT_SZ / TILE_X, OUT_SZ / TILE_Y, 8 * 64);   // (7, 16, 512)
    dim3 block(NTHREADS, 1, 1);
    hipLaunchKernelGGL(CenterDependentPool2D_kernel, grid, block, 0, stream, x, out);
}

// Round 3
// 761.388 us; speedup vs baseline: 1.0972x; 1.0653x over previous
//
#include <hip/hip_runtime.h>
#include <climits>

// CenterDependentPool2D: out[b,c,oy,ox] = max over k x k window (stride 2,
// reflect pad, pad_lo=(k-1)/2) where k by d2 = (oy-112)^2+(ox-112)^2:
//   d2<3600 -> 2 | <5625 -> 8 | <8100 -> 14 | <11025 -> 20 | else 26
// All k even.  Round-0 structure (TILE_Y=16, H-first pipeline) with:
//  (a) frame base aligned DOWN: x_al = 2*ox0 - PLT - D, D = (-PLT) mod 4,
//      so EVERY tile stages with guarded float4 loads; D folds into the
//      ring's horizontal window offset OX = (KMAX-K)/2 + D (vertical
//      offset OY = (KMAX-K)/2 unchanged).
//  (b) kmax==2 tiles bypass LDS entirely (pure 2x2 stride-2 pooling,
//      every input read exactly once -> direct global->global).
//  (c) K=2 ring inside mixed tiles folds the trivial VP stage into V.
// Pipeline per ring:
//   H[hr] = horizontal K-window of T row (tbase+hr)   (nh = 2*rows-2+K rows)
//   VP[v] = max(H[2v], H[2v+1])                       (nv = rows-1+K/2 rows)
//   out[lr]= max_{j<K/2} VP[lr+j]  + per-pixel ring mask

#define IN_SZ 448
#define OUT_SZ 224
#define CENTER 112
#define TILE_X 32
#define TILE_Y 16          // 112 = 16*7 -> tiles never straddle the center row
#define TSTR 92            // multiple of 4 -> f4-aligned T rows
#define HSTR 32
#define NTHREADS 256

#define T_ROWS 56          // 2*(TILE_Y-1) + 26
#define H_ROWS 56
#define VP_ROWS 28

__device__ __forceinline__ int reflect448(int g) {
    g = (g < 0) ? -g : g;
    g = (g >= IN_SZ) ? (2 * IN_SZ - 2 - g) : g;
    return g;
}

__device__ __forceinline__ int ring_k(int d2) {
    if (d2 < 3600)  return 2;
    if (d2 < 5625)  return 8;
    if (d2 < 8100)  return 14;
    if (d2 < 11025) return 20;
    return 26;
}

__device__ __forceinline__ int isqrt_floor(int v) {   // exact, v in [0, ~1e6]
    int s = (int)sqrtf((float)v);
    if (s > 0 && s * s > v) --s;
    if ((s + 1) * (s + 1) <= v) ++s;
    return s;
}

__device__ __forceinline__ float4 max4(float4 a, float4 b) {
    return make_float4(fmaxf(a.x, b.x), fmaxf(a.y, b.y),
                       fmaxf(a.z, b.z), fmaxf(a.w, b.w));
}

template <int K, int KMAX>
__device__ __forceinline__ void ring_pass(
    const float* __restrict__ T, float* __restrict__ H, float* __restrict__ VP,
    float* __restrict__ op, int tid, int lyA, int lyB, int ox0, int oy0)
{
    constexpr int PLT = KMAX / 2 - 1;       // pad_lo of kmax
    constexpr int D   = (4 - (PLT & 3)) & 3;
    constexpr int OX  = (KMAX - K) / 2 + D; // horiz window offset in frame
    constexpr int OY  = (KMAX - K) / 2;     // vert  window offset in frame
    constexpr int KH  = K / 2;              // pairs per window
    constexpr int S   = OX & 3;             // sub-f4 shift of window base
    constexpr int NF  = S + K + 6;          // floats needed per 4-output task
    constexpr int R   = (NF + 3) >> 2;      // f4 reads per task
    constexpr int B0  = (OX - S) >> 2;      // f4 offset of aligned base

    const int rows  = lyB - lyA + 1;
    const int nh    = 2 * (rows - 1) + K;   // H rows needed
    const int nv    = rows - 1 + KH;        // VP rows needed
    const int tbase = 2 * lyA + OY;         // T row of H row 0

    // ---- horizontal windows: 4 outputs per task, aligned f4 reads ----
    for (int t = tid; t < nh * 8; t += NTHREADS) {
        const int hr = t >> 3, g = t & 7;
        const float4* trow = (const float4*)&T[(tbase + hr) * TSTR];
        float f[4 * R];
#pragma unroll
        for (int q = 0; q < R; ++q)
            *(float4*)&f[4 * q] = trow[2 * g + B0 + q];
        float p[KH + 3];                      // register pair pre-reduce
#pragma unroll
        for (int j = 0; j < KH + 3; ++j)
            p[j] = fmaxf(f[S + 2 * j], f[S + 2 * j + 1]);
        float4 W;
        if constexpr (KH == 1) {
            W = make_float4(p[0], p[1], p[2], p[3]);
        } else {                              // KH in {4,7,10,13}
            float core = p[3];
#pragma unroll
            for (int j = 4; j < KH; ++j) core = fmaxf(core, p[j]);
            W.x = fmaxf(fmaxf(p[0], p[1]), fmaxf(p[2], core));
            W.y = fmaxf(fmaxf(p[1], p[2]), fmaxf(core, p[KH]));
            W.z = fmaxf(fmaxf(p[2], core), fmaxf(p[KH], p[KH + 1]));
            W.w = fmaxf(fmaxf(core, p[KH]), fmaxf(p[KH + 1], p[KH + 2]));
        }
        *(float4*)&H[hr * HSTR + 4 * g] = W;  // dense, conflict-free
    }
    __syncthreads();

    if constexpr (KH == 1) {
        // ---- K=2: fold VP into V (one pair per output row) ----
        for (int t = tid; t < rows * 8; t += NTHREADS) {
            const int lr = t >> 3, g = t & 7;
            float4 m = max4(*(const float4*)&H[(2 * lr) * HSTR + 4 * g],
                            *(const float4*)&H[(2 * lr + 1) * HSTR + 4 * g]);
            const int oy  = oy0 + lyA + lr;
            const int dy2 = (oy - CENTER) * (oy - CENTER);
            const int oxb = ox0 + 4 * g;
            float* orow = op + (size_t)oy * OUT_SZ + oxb;
            const float mv[4] = {m.x, m.y, m.z, m.w};
#pragma unroll
            for (int e = 0; e < 4; ++e) {
                const int dx = oxb + e - CENTER;
                if (ring_k(dy2 + dx * dx) == K) orow[e] = mv[e];
            }
        }
        __syncthreads();   // protects H before the next ring's H-build
    } else {
        // ---- vertical pairs of H ----
        for (int t = tid; t < nv * 8; t += NTHREADS) {
            const int v = t >> 3, g = t & 7;
            float4 a = *(const float4*)&H[(2 * v) * HSTR + 4 * g];
            float4 b = *(const float4*)&H[(2 * v + 1) * HSTR + 4 * g];
            *(float4*)&VP[v * HSTR + 4 * g] = max4(a, b);
        }
        __syncthreads();

        // ---- vertical windows + per-pixel masked global store ----
        for (int t = tid; t < rows * 8; t += NTHREADS) {
            const int lr = t >> 3, g = t & 7;
            float4 m = *(const float4*)&VP[lr * HSTR + 4 * g];
#pragma unroll
            for (int j = 1; j < KH; ++j)
                m = max4(m, *(const float4*)&VP[(lr + j) * HSTR + 4 * g]);
            const int oy  = oy0 + lyA + lr;
            const int dy2 = (oy - CENTER) * (oy - CENTER);
            const int oxb = ox0 + 4 * g;
            float* orow = op + (size_t)oy * OUT_SZ + oxb;
            const float mv[4] = {m.x, m.y, m.z, m.w};
#pragma unroll
            for (int e = 0; e < 4; ++e) {
                const int dx = oxb + e - CENTER;
                if (ring_k(dy2 + dx * dx) == K) orow[e] = mv[e];
            }
        }
        // no trailing sync: next ring's H-build writes H (not VP); its
        // post-H barrier orders this V-stage before the next VP overwrite.
    }
}

template <int KMAX>
__device__ __forceinline__ void stage_and_run(
    float* __restrict__ T, float* __restrict__ H, float* __restrict__ VP,
    const float* __restrict__ in, float* __restrict__ op,
    int tid, const int* lyA, const int* lyB, int ox0, int oy0)
{
    constexpr int PLT = KMAX / 2 - 1;
    constexpr int D   = (4 - (PLT & 3)) & 3;     // PLT+D multiple of 4
    constexpr int SPX = 2 * (TILE_X - 1) + KMAX + D;
    constexpr int GPR = (SPX + 3) >> 2;          // f4 groups per staged row
    constexpr int SPY = 2 * (TILE_Y - 1) + KMAX; // staged rows (<= 56)

    // x_al = 2*ox0 - PLT - D is 0 mod 4 (2*ox0 is a multiple of 64)
    const int x_al  = 2 * ox0 - PLT - D;
    const int y_org = 2 * oy0 - PLT;

    for (int t = tid; t < SPY * GPR; t += NTHREADS) {
        const int r = t / GPR, c4 = (t - r * GPR) * 4;   // GPR constexpr
        const int gy = y_org + r, gx = x_al + c4;
        float4 v;
        if ((unsigned)gy < IN_SZ && (unsigned)gx <= IN_SZ - 4) {
            v = *(const float4*)(in + (size_t)gy * IN_SZ + gx);
        } else {
            const float* rowp = in + (size_t)reflect448(gy) * IN_SZ;
            v.x = rowp[reflect448(gx + 0)];
            v.y = rowp[reflect448(gx + 1)];
            v.z = rowp[reflect448(gx + 2)];
            v.w = rowp[reflect448(gx + 3)];
        }
        *(float4*)&T[r * TSTR + c4] = v;
    }
    __syncthreads();

    if (lyA[0] <= lyB[0])
        ring_pass<2, KMAX>(T, H, VP, op, tid, lyA[0], lyB[0], ox0, oy0);
    if constexpr (KMAX >= 8)
        if (lyA[1] <= lyB[1])
            ring_pass<8, KMAX>(T, H, VP, op, tid, lyA[1], lyB[1], ox0, oy0);
    if constexpr (KMAX >= 14)
        if (lyA[2] <= lyB[2])
            ring_pass<14, KMAX>(T, H, VP, op, tid, lyA[2], lyB[2], ox0, oy0);
    if constexpr (KMAX >= 20)
        if (lyA[3] <= lyB[3])
            ring_pass<20, KMAX>(T, H, VP, op, tid, lyA[3], lyB[3], ox0, oy0);
    if constexpr (KMAX >= 26)
        if (lyA[4] <= lyB[4])
            ring_pass<26, KMAX>(T, H, VP, op, tid, lyA[4], lyB[4], ox0, oy0);
}

__global__ __launch_bounds__(NTHREADS, 4)
void CenterDependentPool2D_kernel(const float* __restrict__ x,
                                  float* __restrict__ out)
{
    __shared__ float T[T_ROWS * TSTR];      // 20,608 B
    __shared__ float H[H_ROWS * HSTR];      //  7,168 B
    __shared__ float VP[VP_ROWS * HSTR];    //  3,584 B -> 31,360 B total

    const int tid = threadIdx.x;
    const int ox0 = blockIdx.x * TILE_X;
    const int oy0 = blockIdx.y * TILE_Y;
    const int plane = blockIdx.z;

    const float* __restrict__ in = x + (size_t)plane * IN_SZ * IN_SZ;
    float* __restrict__ op = out + (size_t)plane * OUT_SZ * OUT_SZ;

    // dx^2 range over this tile's columns
    const int a = ox0 - CENTER, b = ox0 + TILE_X - 1 - CENTER;
    int xmn2, xmx2;
    if (a > 0)      { xmn2 = a * a; xmx2 = b * b; }
    else if (b < 0) { xmn2 = b * b; xmx2 = a * a; }
    else            { xmn2 = 0; const int m = (-a > b) ? -a : b; xmx2 = m * m; }

    const int R2a[5] = {0, 3600, 5625, 8100, 11025};
    const int R2b[5] = {3600, 5625, 8100, 11025, INT_MAX};
    const int KS[5]  = {2, 8, 14, 20, 26};

    // per-ring output-row intervals [lyA, lyB] (conservative-safe; the
    // per-pixel ring_k mask in the V stage guarantees exact coverage)
    int lyA[5], lyB[5];
    int kmax = 2;
    const int d0 = oy0 - CENTER;       // oy0 = 16*j; tiles never straddle 112
#pragma unroll
    for (int i = 0; i < 5; ++i) {
        int A = 1, B = 0;
        int shi;
        bool nonempty;
        if (i == 4) { shi = 1000; nonempty = true; }
        else {
            const int hi2 = R2b[i] - 1 - xmn2;
            nonempty = (hi2 >= 0);
            shi = nonempty ? isqrt_floor(hi2) : 0;
        }
        if (nonempty) {
            const int lo2 = R2a[i] - xmx2;
            const int slo = (lo2 <= 0) ? 0 : isqrt_floor(lo2 - 1) + 1;
            if (d0 >= 0) { A = slo - d0; B = shi - d0; }
            else         { const int dp = -d0; A = dp - shi; B = dp - slo; }
            A = A < 0 ? 0 : A;
            B = B > TILE_Y - 1 ? TILE_Y - 1 : B;
        }
        lyA[i] = A; lyB[i] = B;
        if (A <= B) kmax = KS[i];
    }

    if (kmax == 2) {
        // Entire tile is 2x2 stride-2 pooling: zero input reuse, window rows
        // 2*oy..2*oy+1 always in [0,447] -> direct global->global, no LDS.
        for (int t = tid; t < TILE_Y * 8; t += NTHREADS) {
            const int ly = t >> 3, g = t & 7;
            const float* r0 = in + (size_t)(2 * (oy0 + ly)) * IN_SZ
                                 + 2 * ox0 + 8 * g;       // 8-aligned
            const float* r1 = r0 + IN_SZ;
            const float4 a0 = *(const float4*)r0;
            const float4 b0 = *(const float4*)(r0 + 4);
            const float4 a1 = *(const float4*)r1;
            const float4 b1 = *(const float4*)(r1 + 4);
            float4 o;
            o.x = fmaxf(fmaxf(a0.x, a0.y), fmaxf(a1.x, a1.y));
            o.y = fmaxf(fmaxf(a0.z, a0.w), fmaxf(a1.z, a1.w));
            o.z = fmaxf(fmaxf(b0.x, b0.y), fmaxf(b1.x, b1.y));
            o.w = fmaxf(fmaxf(b0.z, b0.w), fmaxf(b1.z, b1.w));
            *(float4*)(op + (size_t)(oy0 + ly) * OUT_SZ + ox0 + 4 * g) = o;
        }
        return;
    }

    switch (kmax) {
        case 8:  stage_and_run<8 >(T, H, VP, in, op, tid, lyA, lyB, ox0, oy0); break;
        case 14: stage_and_run<14>(T, H, VP, in, op, tid, lyA, lyB, ox0, oy0); break;
        case 20: stage_and_run<20>(T, H, VP, in, op, tid, lyA, lyB, ox0, oy0); break;
        default: stage_and_run<26>(T, H, VP, in, op, tid, lyA, lyB, ox0, oy0); break;
    }
}

extern "C" void kernel_launch(void* const* d_in, const int* in_sizes, int n_in,
                              void* d_out, int out_size, void* d_ws, size_t ws_size,
                              hipStream_t stream) {
    const float* x = (const float*)d_in[0];
    float* out = (float*)d_out;
    dim3 grid(OUT_SZ / TILE_X, OUT_SZ / TILE_Y, 8 * 64);   // (7, 14, 512)
    dim3 block(NTHREADS, 1, 1);
    hipLaunchKernelGGL(CenterDependentPool2D_kernel, grid, block, 0, stream, x, out);
}